// Round 1
// baseline (130324.829 us; speedup 1.0000x reference)
//
#include <hip/hip_runtime.h>
#include <cstdint>

#define SCOPE __HIP_MEMORY_SCOPE_AGENT

__device__ __forceinline__ float aload(const float* p) {
  return __hip_atomic_load(p, __ATOMIC_RELAXED, SCOPE);
}
__device__ __forceinline__ void astore(float* p, float v) {
  __hip_atomic_store(p, v, __ATOMIC_RELAXED, SCOPE);
}
__device__ __forceinline__ unsigned cload(const unsigned* p) {
  return __hip_atomic_load(p, __ATOMIC_ACQUIRE, SCOPE);
}
__device__ __forceinline__ void cadd(unsigned* p) {
  __hip_atomic_fetch_add(p, 1u, __ATOMIC_RELEASE, SCOPE);
}
__device__ __forceinline__ float sigm(float x) { return 1.f / (1.f + __expf(-x)); }
__device__ __forceinline__ float tanh_(float x) { return 1.f - 2.f / (__expf(2.f * x) + 1.f); }

// workspace float-offsets
#define Y0R 0      // y0 ring: 4 slots x 512   (h0 of layer0 == y0)
#define Y1R 2048   // y1 ring: 4 slots x 512
#define H1R 4096   // h1 ring: 4 slots x 512
#define XR  6144   // x  ring: 4 slots x 256   (fed-back model input)
#define CTR 7168   // counters: c0 @ +0, c1 @ +64, cx @ +128 (float offsets)

__global__ void mg_init(float* __restrict__ ws, const float* __restrict__ emb,
                        const int* __restrict__ tempo, const int* __restrict__ keysig,
                        const int* __restrict__ lenp) {
  const int tid = blockIdx.x * blockDim.x + threadIdx.x;
  const int n = gridDim.x * blockDim.x;
  for (int i = tid; i < 6144; i += n) astore(ws + i, 0.f);
  // x ring: slots 0..2 = embedding rows [tempo, key_sig, length]; slot 3 = 0
  for (int i = tid; i < 1024; i += n) {
    const int s = i >> 8, j = i & 255;
    float v = 0.f;
    if (s < 3) {
      const int r = (s == 0) ? tempo[0] : ((s == 1) ? keysig[0] : lenp[0]);
      v = emb[r * 256 + j];
    }
    astore(ws + XR + i, v);
  }
  if (tid == 0) {
    __hip_atomic_store((unsigned*)(ws + CTR), 0u, __ATOMIC_RELAXED, SCOPE);
    __hip_atomic_store((unsigned*)(ws + CTR + 64), 0u, __ATOMIC_RELAXED, SCOPE);
    // cx starts at 24 == "x[0..2] ready" (3 virtual out-cells x 8 blocks)
    __hip_atomic_store((unsigned*)(ws + CTR + 128), 24u, __ATOMIC_RELAXED, SCOPE);
  }
}

// Roles: blocks [0,32) layer0, [32,64) layer1, [64,72) output projection.
// Counters (monotone): c0 = 32*(U+1) after L0 finishes cell U; c1 likewise for L1;
// cx = 24 + 8*(V+1) after OUT finishes cell V.
// L0 cell u waits: c0>=32u (full h0[u-1]), cx>=8(u+1) (x[u] ready; implies L1 done u-3).
// L1 cell v waits: c0>=32(v+1) (y0[v]), c1>=32v (h1[v-1]), cx>=8v (y1 ring slot free).
// OUT cell v waits: c1>=32(v+1) (y1[v]).
__global__ __launch_bounds__(512, 2) void mg_main(
    float* __restrict__ ws,
    const float* __restrict__ Wih0, const float* __restrict__ Whh0,
    const float* __restrict__ bih0, const float* __restrict__ bhh0,
    const float* __restrict__ Wih1, const float* __restrict__ Whh1,
    const float* __restrict__ bih1, const float* __restrict__ bhh1,
    const float* __restrict__ Wp, const float* __restrict__ bp,
    const float* __restrict__ Wv, const float* __restrict__ bv,
    const int* __restrict__ lenp, float* __restrict__ dout) {
  const int bid = blockIdx.x;
  const int tid = threadIdx.x;
  const int wv = tid >> 6;   // wave 0..7
  const int l = tid & 63;    // lane
  const int NT = 3 * lenp[0] * 128;
  float* y0r = ws + Y0R;
  float* y1r = ws + Y1R;
  float* h1r = ws + H1R;
  float* xr = ws + XR;
  unsigned* c0 = (unsigned*)(ws + CTR);
  unsigned* c1 = (unsigned*)(ws + CTR + 64);
  unsigned* cx = (unsigned*)(ws + CTR + 128);
  __shared__ float hbuf[1024];

  if (bid < 32) {
    // ================= layer 0 =================
    // block owns h0[k], k in [16*bid, 16*bid+16); wave owns 2 k's.
    // thread tile: 8 rows (2 k x 4 gates) x 12 col-chunks, col = l + 64*j.
    // cols 0..511 -> Whh0 (times h0_prev), 512..767 -> Wih0 (times x).
    const int beta = bid;
    float w[96], base[8];
    float cst0 = 0.f, cst1 = 0.f;
#pragma unroll
    for (int r = 0; r < 8; ++r) {
      const int row = ((r & 3) << 9) + (beta << 4) + (wv << 1) + (r >> 2);
      base[r] = bih0[row] + bhh0[row];
#pragma unroll
      for (int j = 0; j < 12; ++j) {
        const int c = l + (j << 6);
        w[r * 12 + j] = (j < 8) ? Whh0[row * 512 + c] : Wih0[(row << 8) + (c - 512)];
      }
    }
    for (int u = 0; u < NT; ++u) {
      const int slot = u & 3;
      if (tid == 0) {
        const unsigned n0 = 32u * (unsigned)u;
        while (cload(c0) < n0) __builtin_amdgcn_s_sleep(1);
        const unsigned nx = 8u * (unsigned)(u + 1);
        while (cload(cx) < nx) __builtin_amdgcn_s_sleep(1);
      }
      __syncthreads();
      const float* hp = y0r + ((u + 3) & 3) * 512;
      const float* xp = xr + slot * 256;
      for (int i = tid; i < 768; i += 512)
        hbuf[i] = (i < 512) ? aload(hp + i) : aload(xp + (i - 512));
      __syncthreads();
      float acc[8] = {0.f, 0.f, 0.f, 0.f, 0.f, 0.f, 0.f, 0.f};
#pragma unroll
      for (int j = 0; j < 12; ++j) {
        const float hv = hbuf[(j << 6) + l];
#pragma unroll
        for (int r = 0; r < 8; ++r) acc[r] = fmaf(w[r * 12 + j], hv, acc[r]);
      }
#pragma unroll
      for (int r = 0; r < 8; ++r) {
        float v = acc[r];
#pragma unroll
        for (int off = 32; off > 0; off >>= 1) v += __shfl_xor(v, off, 64);
        acc[r] = v + base[r];
      }
      float hn0, hn1;
      {
        const float cn = sigm(acc[1]) * cst0 + sigm(acc[0]) * tanh_(acc[2]);
        cst0 = cn;
        hn0 = sigm(acc[3]) * tanh_(cn);
      }
      {
        const float cn = sigm(acc[5]) * cst1 + sigm(acc[4]) * tanh_(acc[6]);
        cst1 = cn;
        hn1 = sigm(acc[7]) * tanh_(cn);
      }
      if (l < 2) astore(y0r + slot * 512 + (beta << 4) + (wv << 1) + l, l ? hn1 : hn0);
      __syncthreads();
      if (tid == 0) cadd(c0);
    }
  } else if (bid < 64) {
    // ================= layer 1 =================
    // cols 0..511 -> Wih1 (times y0[v]), 512..1023 -> Whh1 (times h1[v-1]).
    const int beta = bid - 32;
    float w[128], base[8];
    float cst0 = 0.f, cst1 = 0.f;
#pragma unroll
    for (int r = 0; r < 8; ++r) {
      const int row = ((r & 3) << 9) + (beta << 4) + (wv << 1) + (r >> 2);
      base[r] = bih1[row] + bhh1[row];
#pragma unroll
      for (int j = 0; j < 16; ++j) {
        const int c = l + (j << 6);
        w[r * 16 + j] = (j < 8) ? Wih1[row * 512 + c] : Whh1[row * 512 + (c - 512)];
      }
    }
    for (int v = 0; v < NT; ++v) {
      const int slot = v & 3;
      if (tid == 0) {
        const unsigned n0 = 32u * (unsigned)(v + 1);
        while (cload(c0) < n0) __builtin_amdgcn_s_sleep(1);
        const unsigned n1 = 32u * (unsigned)v;
        while (cload(c1) < n1) __builtin_amdgcn_s_sleep(1);
        const unsigned nx = 8u * (unsigned)v;
        while (cload(cx) < nx) __builtin_amdgcn_s_sleep(1);
      }
      __syncthreads();
      const float* yp = y0r + slot * 512;
      const float* hp = h1r + ((v + 3) & 3) * 512;
      hbuf[tid] = aload(yp + tid);
      hbuf[tid + 512] = aload(hp + tid);
      __syncthreads();
      float acc[8] = {0.f, 0.f, 0.f, 0.f, 0.f, 0.f, 0.f, 0.f};
#pragma unroll
      for (int j = 0; j < 16; ++j) {
        const float hv = hbuf[(j << 6) + l];
#pragma unroll
        for (int r = 0; r < 8; ++r) acc[r] = fmaf(w[r * 16 + j], hv, acc[r]);
      }
#pragma unroll
      for (int r = 0; r < 8; ++r) {
        float v2 = acc[r];
#pragma unroll
        for (int off = 32; off > 0; off >>= 1) v2 += __shfl_xor(v2, off, 64);
        acc[r] = v2 + base[r];
      }
      float hn0, hn1;
      {
        const float cn = sigm(acc[1]) * cst0 + sigm(acc[0]) * tanh_(acc[2]);
        cst0 = cn;
        hn0 = sigm(acc[3]) * tanh_(cn);
      }
      {
        const float cn = sigm(acc[5]) * cst1 + sigm(acc[4]) * tanh_(acc[6]);
        cst1 = cn;
        hn1 = sigm(acc[7]) * tanh_(cn);
      }
      if (l < 2) {
        const int kg = (beta << 4) + (wv << 1) + l;
        const float hv = l ? hn1 : hn0;
        astore(h1r + slot * 512 + kg, hv);
        astore(y1r + slot * 512 + kg, hv);
      }
      __syncthreads();
      if (tid == 0) cadd(c1);
    }
  } else {
    // ================= output projection =================
    // out[v] = [Wp;Wv] @ y1[v] + [bp;bv]; also publishes x[v+3] ring slot.
    const int b = bid - 64;
    float w[32], bs[4];
#pragma unroll
    for (int r = 0; r < 4; ++r) {
      const int row = (b << 5) + (wv << 2) + r;
      bs[r] = (row < 128) ? bp[row] : bv[row - 128];
#pragma unroll
      for (int j = 0; j < 8; ++j) {
        const int c = l + (j << 6);
        w[r * 8 + j] = (row < 128) ? Wp[(row << 9) + c] : Wv[((row - 128) << 9) + c];
      }
    }
    for (int v = 0; v < NT; ++v) {
      const int slot = v & 3;
      if (tid == 0) {
        const unsigned n1 = 32u * (unsigned)(v + 1);
        while (cload(c1) < n1) __builtin_amdgcn_s_sleep(1);
      }
      __syncthreads();
      hbuf[tid] = aload(y1r + slot * 512 + tid);
      __syncthreads();
      float a0 = 0.f, a1 = 0.f, a2 = 0.f, a3 = 0.f;
#pragma unroll
      for (int j = 0; j < 8; ++j) {
        const float hv = hbuf[(j << 6) + l];
        a0 = fmaf(w[0 * 8 + j], hv, a0);
        a1 = fmaf(w[1 * 8 + j], hv, a1);
        a2 = fmaf(w[2 * 8 + j], hv, a2);
        a3 = fmaf(w[3 * 8 + j], hv, a3);
      }
#pragma unroll
      for (int off = 32; off > 0; off >>= 1) {
        a0 += __shfl_xor(a0, off, 64);
        a1 += __shfl_xor(a1, off, 64);
        a2 += __shfl_xor(a2, off, 64);
        a3 += __shfl_xor(a3, off, 64);
      }
      if (l < 4) {
        const int row = (b << 5) + (wv << 2) + l;
        const float val = (l == 0) ? a0 + bs[0]
                        : (l == 1) ? a1 + bs[1]
                        : (l == 2) ? a2 + bs[2]
                                   : a3 + bs[3];
        dout[(size_t)v * 256 + row] = val;
        astore(xr + ((v + 3) & 3) * 256 + row, val);
      }
      __syncthreads();
      if (tid == 0) cadd(cx);
    }
  }
}

extern "C" void kernel_launch(void* const* d_in, const int* in_sizes, int n_in,
                              void* d_out, int out_size, void* d_ws, size_t ws_size,
                              hipStream_t stream) {
  const int* tempo = (const int*)d_in[0];
  const int* keysig = (const int*)d_in[1];
  const int* lenp = (const int*)d_in[2];
  const float* emb = (const float*)d_in[3];
  const float* Wih0 = (const float*)d_in[4];
  const float* Whh0 = (const float*)d_in[5];
  const float* bih0 = (const float*)d_in[6];
  const float* bhh0 = (const float*)d_in[7];
  const float* Wih1 = (const float*)d_in[8];
  const float* Whh1 = (const float*)d_in[9];
  const float* bih1 = (const float*)d_in[10];
  const float* bhh1 = (const float*)d_in[11];
  const float* Wp = (const float*)d_in[12];
  const float* bp = (const float*)d_in[13];
  const float* Wv = (const float*)d_in[14];
  const float* bv = (const float*)d_in[15];
  float* ws = (float*)d_ws;
  float* out = (float*)d_out;

  mg_init<<<16, 256, 0, stream>>>(ws, emb, tempo, keysig, lenp);
  mg_main<<<72, 512, 0, stream>>>(ws, Wih0, Whh0, bih0, bhh0, Wih1, Whh1, bih1, bhh1,
                                  Wp, bp, Wv, bv, lenp, out);
}